// Round 17
// baseline (122.174 us; speedup 1.0000x reference)
//
#include <hip/hip_runtime.h>

#define BB 16
#define SS 2048
#define DD 64
#define L2E 1.44269504f
#define A3C 4.32808512f   // 3 * log2(e)

typedef _Float16 half8 __attribute__((ext_vector_type(8)));
typedef _Float16 half4 __attribute__((ext_vector_type(4)));
typedef float f32x4 __attribute__((ext_vector_type(4)));

typedef const __attribute__((address_space(1))) void* gas_ptr;
typedef __attribute__((address_space(3))) void* las_ptr;

#define SBAR() __builtin_amdgcn_sched_barrier(0)

// counted (non-draining) vmem wait + barrier; segment boundary for the ladders
#define TILE_SYNC(N)                                            \
  do {                                                          \
    asm volatile("s_waitcnt vmcnt(" #N ")" ::: "memory");       \
    __builtin_amdgcn_s_barrier();                               \
    __builtin_amdgcn_sched_barrier(0);                          \
  } while (0)

__device__ __forceinline__ void load_qfrag(const float* __restrict__ Qp,
                                           half8& qa0, half8& qa1) {
  float4 v0 = *(const float4*)(Qp);
  float4 v1 = *(const float4*)(Qp + 4);
  float4 v2 = *(const float4*)(Qp + 32);
  float4 v3 = *(const float4*)(Qp + 36);
  qa0[0] = (_Float16)(v0.x * 0.125f); qa0[1] = (_Float16)(v0.y * 0.125f);
  qa0[2] = (_Float16)(v0.z * 0.125f); qa0[3] = (_Float16)(v0.w * 0.125f);
  qa0[4] = (_Float16)(v1.x * 0.125f); qa0[5] = (_Float16)(v1.y * 0.125f);
  qa0[6] = (_Float16)(v1.z * 0.125f); qa0[7] = (_Float16)(v1.w * 0.125f);
  qa1[0] = (_Float16)(v2.x * 0.125f); qa1[1] = (_Float16)(v2.y * 0.125f);
  qa1[2] = (_Float16)(v2.z * 0.125f); qa1[3] = (_Float16)(v2.w * 0.125f);
  qa1[4] = (_Float16)(v3.x * 0.125f); qa1[5] = (_Float16)(v3.y * 0.125f);
  qa1[6] = (_Float16)(v3.z * 0.125f); qa1[7] = (_Float16)(v3.w * 0.125f);
}

// ---------------- setup: K->f16, V->f16 transposed, AND row-sum partials --------------
// block (b, kt): converts the 64-key K/V tiles; then computes, for ALL 2048 q of batch b,
// partial sum_k exp(s-3) over this block's 64 keys, atomicAdd into Lsum[b][q].
__global__ __launch_bounds__(256) void setup_kernel(const float* __restrict__ K,
                                                    const float* __restrict__ V,
                                                    const float* __restrict__ Q,
                                                    _Float16* __restrict__ Kh,
                                                    _Float16* __restrict__ VT,
                                                    float* __restrict__ Lsum) {
  __shared__ float tile[64][65];
  __shared__ _Float16 Kl[64][80];   // padded stride 160B: 16B-aligned fragments
  int b = blockIdx.x >> 5, kt = blockIdx.x & 31;  // 32 tiles of 64 rows
  int tid = threadIdx.x;
  size_t base = ((size_t)b * SS + (size_t)kt * 64) * DD;
  const float4* Kq = (const float4*)(K + base);
  const float4* Vq = (const float4*)(V + base);
  half4* Khq = (half4*)(Kh + base);
#pragma unroll
  for (int it = 0; it < 4; ++it) {
    int i = tid + it * 256;  // quad index 0..1023 over 64x64 tile
    float4 kv = Kq[i];
    half4 h;
    h[0] = (_Float16)kv.x; h[1] = (_Float16)kv.y;
    h[2] = (_Float16)kv.z; h[3] = (_Float16)kv.w;
    Khq[i] = h;
    int row = i >> 4, c4 = (i & 15) << 2;
    *(half4*)&Kl[row][c4] = h;
    float4 vv = Vq[i];
    tile[row][c4 + 0] = vv.x; tile[row][c4 + 1] = vv.y;
    tile[row][c4 + 2] = vv.z; tile[row][c4 + 3] = vv.w;
  }
  __syncthreads();
  // ---- V transpose out ----
  {
    int d = tid >> 2, seg = tid & 3;  // 64 d-rows x 4 segments of 16 k
    half8 o0, o1;
#pragma unroll
    for (int j = 0; j < 8; ++j) o0[j] = (_Float16)tile[seg * 16 + j][d];
#pragma unroll
    for (int j = 0; j < 8; ++j) o1[j] = (_Float16)tile[seg * 16 + 8 + j][d];
    _Float16* dst = VT + ((size_t)b * DD + d) * SS + (size_t)kt * 64 + seg * 16;
    *(half8*)dst = o0;
    *(half8*)(dst + 8) = o1;
  }
  // ---- row-sum partials over this block's 64 keys ----
  int w = tid >> 6, l = tid & 63, g = l >> 4, c = l & 15;
  half8 kf[4][2];
#pragma unroll
  for (int k2 = 0; k2 < 4; ++k2) {
    kf[k2][0] = *(const half8*)&Kl[k2 * 16 + c][8 * g];       // d 0..31
    kf[k2][1] = *(const half8*)&Kl[k2 * 16 + c][32 + 8 * g];  // d 32..63
  }
  const float* Qb = Q + (size_t)b * SS * DD;
  for (int qt = w; qt < 128; qt += 4) {   // 32 q-tiles per wave
    half8 qa0, qa1;
    load_qfrag(Qb + (size_t)(qt * 16 + c) * DD + 8 * g, qa0, qa1);
    float sum = 0.f;
#pragma unroll
    for (int k2 = 0; k2 < 4; ++k2) {
      f32x4 s = {0.f, 0.f, 0.f, 0.f};
      s = __builtin_amdgcn_mfma_f32_16x16x32_f16(kf[k2][0], qa0, s, 0, 0, 0);
      s = __builtin_amdgcn_mfma_f32_16x16x32_f16(kf[k2][1], qa1, s, 0, 0, 0);
      sum += exp2f(fmaf(s[0], L2E, -A3C)) + exp2f(fmaf(s[1], L2E, -A3C)) +
             exp2f(fmaf(s[2], L2E, -A3C)) + exp2f(fmaf(s[3], L2E, -A3C));
    }
    sum += __shfl_xor(sum, 16);
    sum += __shfl_xor(sum, 32);
    if (l < 16) atomicAdd(&Lsum[(size_t)b * SS + qt * 16 + l], sum);
  }
}

// Stage one 64x64 f16 tile into an 8KB LDS slab with a 2-wave (128-thread) block.
// XOR-swizzle applied on the GLOBAL source (global_load_lds writes lane-linear).
// 4 x 16B loads per thread; wave w covers rows w*32 .. w*32+31.
__device__ __forceinline__ void stage64(const _Float16* __restrict__ gbase, size_t rstride,
                                        _Float16* lds, int tid) {
  int w = tid >> 6, lam = tid & 63;
#pragma unroll
  for (int a = 0; a < 4; ++a) {
    int rloc = lam >> 3;                              // 0..7 (== r & 7)
    int r = w * 32 + a * 8 + rloc;
    int byt = ((lam & 7) * 16) ^ (rloc << 4);         // swizzled byte-in-row
    const _Float16* g = gbase + (size_t)r * rstride + (byt >> 1);
    _Float16* lp = lds + (w * 32 + a * 8) * 64;       // wave-uniform base
    __builtin_amdgcn_global_load_lds((gas_ptr)g, (las_ptr)lp, 16, 0, 0);
  }
}

// ---------------- fused attention: single sweep, exact counted vmcnt ----------------
// wg = 2 waves x 16 q-rows = 32 rows; waves share 4 x 8KB staged slabs, sweep all k.
__global__ __launch_bounds__(128, 2) void attn_kernel(const float* __restrict__ Q,
                                                      const _Float16* __restrict__ Kh,
                                                      const _Float16* __restrict__ VT,
                                                      const float* __restrict__ Lsum,
                                                      float* __restrict__ ctx_out,
                                                      float* __restrict__ attn_out) {
  __shared__ __attribute__((aligned(16))) _Float16 slab[4][64 * 64];  // 32KB total

  int tid = threadIdx.x;
  int w = tid >> 6, l = tid & 63, g = l >> 4, c = l & 15;
  int bid = (int)blockIdx.x;
  int remap = (bid & 7) * 128 + (bid >> 3);   // XCD-contiguous (1024 grid)
  int b = remap >> 6, qb = remap & 63;
  size_t qr = (size_t)b * SS + (size_t)qb * 32 + (size_t)w * 16;
  const _Float16* KB = Kh + (size_t)b * SS * DD;
  const _Float16* VB = VT + (size_t)b * DD * SS;
  int swz = (c & 7) << 4;

  // ---- prologue (pinned order: Q+Ls | KV0 | KV1); K slabs {0,1}, V slabs {2,3} ----
  half8 qa0, qa1;
  load_qfrag(Q + (qr + c) * DD + 8 * g, qa0, qa1);
  float lsum = Lsum[qr + c];
  SBAR();
  stage64(KB, DD, slab[0], tid);
  stage64(VB, SS, slab[2], tid);
  SBAR();
  stage64(KB + (size_t)64 * DD, DD, slab[1], tid);
  stage64(VB + 64, SS, slab[3], tid);
  SBAR();
  float ac = -__log2f(lsum) - A3C;  // p/l = exp2(s*L2E + ac)

  // ---- single sweep: S, normalized attn write, PV; 2+2 slabs, depth-1 ----
  // Ladder: t=0: [Q4,Ls1,KV0 8,KV1 8] -> vmcnt(8) retires through KV0;
  // t>=1: [KV(t) 8, st(t-1) 4] -> vmcnt(4) retires KV(t), store acks ride.
  // Seg(t), 1<=t<=30, pinned: stage KV(t+1) (slab parity; WAR-safe past sync(t)),
  // then compute(t).
  f32x4 cacc[4] = {{0.f, 0.f, 0.f, 0.f}, {0.f, 0.f, 0.f, 0.f},
                   {0.f, 0.f, 0.f, 0.f}, {0.f, 0.f, 0.f, 0.f}};
  for (int t = 0; t < 32; ++t) {
    if (t == 0) TILE_SYNC(8); else TILE_SYNC(4);
    if (t >= 1 && t <= 30) {
      stage64(KB + (size_t)(t + 1) * 64 * DD, DD, slab[(t + 1) & 1], tid);
      stage64(VB + (size_t)(t + 1) * 64, SS, slab[2 + ((t + 1) & 1)], tid);
      SBAR();
    }
    const _Float16* kl = slab[t & 1];
    const _Float16* vl = slab[2 + (t & 1)];
#pragma unroll
    for (int kt = 0; kt < 4; ++kt) {
      const _Float16* kb = kl + (kt * 16 + c) * 64;
      half8 kf0 = *(const half8*)(kb + (((16 * g) ^ swz) >> 1));
      half8 kf1 = *(const half8*)(kb + (((64 + 16 * g) ^ swz) >> 1));
      f32x4 s = {0.f, 0.f, 0.f, 0.f};
      s = __builtin_amdgcn_mfma_f32_16x16x32_f16(kf0, qa0, s, 0, 0, 0);
      s = __builtin_amdgcn_mfma_f32_16x16x32_f16(kf1, qa1, s, 0, 0, 0);

      float p0 = exp2f(fmaf(s[0], L2E, ac));
      float p1 = exp2f(fmaf(s[1], L2E, ac));
      float p2 = exp2f(fmaf(s[2], L2E, ac));
      float p3 = exp2f(fmaf(s[3], L2E, ac));
      f32x4 st = {p0, p1, p2, p3};
      *(f32x4*)(attn_out + (qr + c) * SS + t * 64 + kt * 16 + 4 * g) = st;

      half4 pf;
      pf[0] = (_Float16)p0; pf[1] = (_Float16)p1;
      pf[2] = (_Float16)p2; pf[3] = (_Float16)p3;
#pragma unroll
      for (int dt = 0; dt < 4; ++dt) {
        const _Float16* vb = vl + (dt * 16 + c) * 64;
        half4 vf = *(const half4*)(vb + (((32 * kt + 8 * g) ^ swz) >> 1));
        cacc[dt] = __builtin_amdgcn_mfma_f32_16x16x16f16(pf, vf, cacc[dt], 0, 0, 0);
      }
    }
  }

  // ---- ctx store (wave-local, fully reduced) ----
#pragma unroll
  for (int dt = 0; dt < 4; ++dt)
#pragma unroll
    for (int j = 0; j < 4; ++j)
      ctx_out[(qr + 4 * g + j) * DD + dt * 16 + c] = cacc[dt][j];
}

extern "C" void kernel_launch(void* const* d_in, const int* in_sizes, int n_in,
                              void* d_out, int out_size, void* d_ws, size_t ws_size,
                              hipStream_t stream) {
  const float* q = (const float*)d_in[0];
  const float* k = (const float*)d_in[1];
  const float* v = (const float*)d_in[2];
  float* ctx = (float*)d_out;
  float* attn = ctx + (size_t)BB * SS * DD;
  _Float16* Kh = (_Float16*)d_ws;                   // [B][S][D] f16, 4 MB
  _Float16* VT = Kh + (size_t)BB * SS * DD;         // [B][D][S] f16, 4 MB
  float* Lsum = (float*)(VT + (size_t)BB * DD * SS);  // [B][S] f32, 128 KB
  hipMemsetAsync(Lsum, 0, (size_t)BB * SS * sizeof(float), stream);
  setup_kernel<<<dim3(BB * 32), dim3(256), 0, stream>>>(k, v, q, Kh, VT, Lsum);
  attn_kernel<<<dim3(BB * 64), dim3(128), 0, stream>>>(q, Kh, VT, Lsum, ctx, attn);
}

// Round 18
// 97.980 us; speedup vs baseline: 1.2469x; 1.2469x over previous
//
#include <hip/hip_runtime.h>

#define BB 16
#define SS 2048
#define DD 64
#define L2E 1.44269504f
#define A3C 4.32808512f   // 3 * log2(e)

typedef _Float16 half8 __attribute__((ext_vector_type(8)));
typedef _Float16 half4 __attribute__((ext_vector_type(4)));
typedef float f32x4 __attribute__((ext_vector_type(4)));

typedef const __attribute__((address_space(1))) void* gas_ptr;
typedef __attribute__((address_space(3))) void* las_ptr;

#define SBAR() __builtin_amdgcn_sched_barrier(0)

// counted (non-draining) vmem wait + barrier; segment boundary for the ladders
#define TILE_SYNC(N)                                            \
  do {                                                          \
    asm volatile("s_waitcnt vmcnt(" #N ")" ::: "memory");       \
    __builtin_amdgcn_s_barrier();                               \
    __builtin_amdgcn_sched_barrier(0);                          \
  } while (0)

// ---------------- setup: K -> f16 copy, V -> f16 transposed [b][d][s] ----------------
__global__ __launch_bounds__(256) void setup_kernel(const float* __restrict__ K,
                                                    const float* __restrict__ V,
                                                    _Float16* __restrict__ Kh,
                                                    _Float16* __restrict__ VT) {
  __shared__ float tile[64][65];
  int b = blockIdx.x >> 5, kt = blockIdx.x & 31;  // 32 tiles of 64 rows
  int tid = threadIdx.x;
  size_t base = ((size_t)b * SS + (size_t)kt * 64) * DD;
  const float4* Kq = (const float4*)(K + base);
  const float4* Vq = (const float4*)(V + base);
  half4* Khq = (half4*)(Kh + base);
#pragma unroll
  for (int it = 0; it < 4; ++it) {
    int i = tid + it * 256;  // quad index 0..1023 over 64x64 tile
    float4 kv = Kq[i];
    half4 h;
    h[0] = (_Float16)kv.x; h[1] = (_Float16)kv.y;
    h[2] = (_Float16)kv.z; h[3] = (_Float16)kv.w;
    Khq[i] = h;
    float4 vv = Vq[i];
    int row = i >> 4, c4 = (i & 15) << 2;
    tile[row][c4 + 0] = vv.x; tile[row][c4 + 1] = vv.y;
    tile[row][c4 + 2] = vv.z; tile[row][c4 + 3] = vv.w;
  }
  __syncthreads();
  int d = tid >> 2, seg = tid & 3;  // 64 d-rows x 4 segments of 16 k
  half8 o0, o1;
#pragma unroll
  for (int j = 0; j < 8; ++j) o0[j] = (_Float16)tile[seg * 16 + j][d];
#pragma unroll
  for (int j = 0; j < 8; ++j) o1[j] = (_Float16)tile[seg * 16 + 8 + j][d];
  _Float16* dst = VT + ((size_t)b * DD + d) * SS + (size_t)kt * 64 + seg * 16;
  *(half8*)dst = o0;
  *(half8*)(dst + 8) = o1;
}

// Stage one 64x64 f16 tile into an 8KB LDS slab with a 2-wave (128-thread) block.
// XOR-swizzle applied on the GLOBAL source (global_load_lds writes lane-linear).
// 4 x 16B loads per thread; wave w covers rows w*32 .. w*32+31.
__device__ __forceinline__ void stage64(const _Float16* __restrict__ gbase, size_t rstride,
                                        _Float16* lds, int tid) {
  int w = tid >> 6, lam = tid & 63;
#pragma unroll
  for (int a = 0; a < 4; ++a) {
    int rloc = lam >> 3;                              // 0..7 (== r & 7)
    int r = w * 32 + a * 8 + rloc;
    int byt = ((lam & 7) * 16) ^ (rloc << 4);         // swizzled byte-in-row
    const _Float16* g = gbase + (size_t)r * rstride + (byt >> 1);
    _Float16* lp = lds + (w * 32 + a * 8) * 64;       // wave-uniform base
    __builtin_amdgcn_global_load_lds((gas_ptr)g, (las_ptr)lp, 16, 0, 0);
  }
}

__device__ __forceinline__ void load_qfrag(const float* __restrict__ Qp,
                                           half8& qa0, half8& qa1) {
  float4 v0 = *(const float4*)(Qp);
  float4 v1 = *(const float4*)(Qp + 4);
  float4 v2 = *(const float4*)(Qp + 32);
  float4 v3 = *(const float4*)(Qp + 36);
  qa0[0] = (_Float16)(v0.x * 0.125f); qa0[1] = (_Float16)(v0.y * 0.125f);
  qa0[2] = (_Float16)(v0.z * 0.125f); qa0[3] = (_Float16)(v0.w * 0.125f);
  qa0[4] = (_Float16)(v1.x * 0.125f); qa0[5] = (_Float16)(v1.y * 0.125f);
  qa0[6] = (_Float16)(v1.z * 0.125f); qa0[7] = (_Float16)(v1.w * 0.125f);
  qa1[0] = (_Float16)(v2.x * 0.125f); qa1[1] = (_Float16)(v2.y * 0.125f);
  qa1[2] = (_Float16)(v2.z * 0.125f); qa1[3] = (_Float16)(v2.w * 0.125f);
  qa1[4] = (_Float16)(v3.x * 0.125f); qa1[5] = (_Float16)(v3.y * 0.125f);
  qa1[6] = (_Float16)(v3.z * 0.125f); qa1[7] = (_Float16)(v3.w * 0.125f);
}

// ---------------- fused attention: 2-wave blocks, two sweeps, exact counted vmcnt ------
// wg = 2 waves x 16 q-rows = 32 rows; waves share 4 x 8KB staged slabs, sweep all k.
__global__ __launch_bounds__(128, 2) void attn_kernel(const float* __restrict__ Q,
                                                      const _Float16* __restrict__ Kh,
                                                      const _Float16* __restrict__ VT,
                                                      float* __restrict__ ctx_out,
                                                      float* __restrict__ attn_out) {
  __shared__ __attribute__((aligned(16))) _Float16 slab[4][64 * 64];  // 32KB total

  int tid = threadIdx.x;
  int w = tid >> 6, l = tid & 63, g = l >> 4, c = l & 15;
  int bid = (int)blockIdx.x;
  int remap = (bid & 7) * 128 + (bid >> 3);   // XCD-contiguous (1024 grid, 2 batches/XCD)
  int b = remap >> 6, qb = remap & 63;
  size_t qr = (size_t)b * SS + (size_t)qb * 32 + (size_t)w * 16;
  const _Float16* KB = Kh + (size_t)b * SS * DD;
  const _Float16* VB = VT + (size_t)b * DD * SS;
  int swz = (c & 7) << 4;

  // ---- sweep 1 prologue (pinned order: Q | s0 | s1 | s2; depth 3) ----
  half8 qa0, qa1;
  load_qfrag(Q + (qr + c) * DD + 8 * g, qa0, qa1);
  SBAR();
  stage64(KB, DD, slab[0], tid);
  SBAR();
  stage64(KB + (size_t)64 * DD, DD, slab[1], tid);
  SBAR();
  stage64(KB + (size_t)128 * DD, DD, slab[2], tid);
  SBAR();

  // ---- sweep 1: row sums of exp(s - 3); depth-3, 4 slabs, 4-way accumulators ----
  // Ladder (pinned): t=0: [Q4,s0,s1,s2]=16 -> vmcnt(8) retires Q+s0;
  // steady t<=29: [s(t),s(t+1),s(t+2)]=12 -> vmcnt(8); t=30: vmcnt(4); t=31: vmcnt(0).
  float ls0 = 0.f, ls1 = 0.f, ls2 = 0.f, ls3 = 0.f;
  for (int t = 0; t < 32; ++t) {
    if (t < 30) TILE_SYNC(8);
    else if (t == 30) TILE_SYNC(4);
    else TILE_SYNC(0);
    if (t + 3 < 32) {
      stage64(KB + (size_t)(t + 3) * 64 * DD, DD, slab[(t + 3) & 3], tid);
      SBAR();
    }
    const _Float16* kl = slab[t & 3];
#pragma unroll
    for (int kt = 0; kt < 4; ++kt) {
      const _Float16* kb = kl + (kt * 16 + c) * 64;
      half8 kf0 = *(const half8*)(kb + (((16 * g) ^ swz) >> 1));
      half8 kf1 = *(const half8*)(kb + (((64 + 16 * g) ^ swz) >> 1));
      f32x4 s = {0.f, 0.f, 0.f, 0.f};
      s = __builtin_amdgcn_mfma_f32_16x16x32_f16(kf0, qa0, s, 0, 0, 0);
      s = __builtin_amdgcn_mfma_f32_16x16x32_f16(kf1, qa1, s, 0, 0, 0);
      float e0 = exp2f(fmaf(s[0], L2E, -A3C));
      float e1 = exp2f(fmaf(s[1], L2E, -A3C));
      float e2 = exp2f(fmaf(s[2], L2E, -A3C));
      float e3 = exp2f(fmaf(s[3], L2E, -A3C));
      if (kt == 0) { ls0 += e0 + e1 + e2 + e3; }
      else if (kt == 1) { ls1 += e0 + e1 + e2 + e3; }
      else if (kt == 2) { ls2 += e0 + e1 + e2 + e3; }
      else { ls3 += e0 + e1 + e2 + e3; }
    }
  }
  float lsum = (ls0 + ls1) + (ls2 + ls3);
  lsum += __shfl_xor(lsum, 16);
  lsum += __shfl_xor(lsum, 32);
  float ac = -__log2f(lsum) - A3C;  // p/l = exp2(s*L2E + ac)

  __syncthreads();  // all waves done reading slabs before restage

  // ---- sweep 2 prologue (pinned: KV0 | KV1); K slabs {0,1}, V slabs {2,3} ----
  stage64(KB, DD, slab[0], tid);
  stage64(VB, SS, slab[2], tid);
  SBAR();
  stage64(KB + (size_t)64 * DD, DD, slab[1], tid);
  stage64(VB + 64, SS, slab[3], tid);
  SBAR();

  // ---- sweep 2: recompute S, write normalized attn, PV; 2+2 slabs, depth-1 ----
  // Ladder: t=0: [KV0 8, KV1 8] -> vmcnt(8) retires KV0;
  // t>=1: [st(t-2)?, KV(t), st(t-1)] -> vmcnt(4) retires KV(t) (+old store acks).
  // Seg(t), 1<=t<=30, pinned: stage KV(t+1) first (slab parity (t+1)&1; safe: all
  // waves passed sync(t) so compute(t-1) reads of that slab are done), then compute.
  f32x4 cacc[4] = {{0.f, 0.f, 0.f, 0.f}, {0.f, 0.f, 0.f, 0.f},
                   {0.f, 0.f, 0.f, 0.f}, {0.f, 0.f, 0.f, 0.f}};
  for (int t = 0; t < 32; ++t) {
    if (t == 0) TILE_SYNC(8); else TILE_SYNC(4);
    if (t >= 1 && t <= 30) {
      stage64(KB + (size_t)(t + 1) * 64 * DD, DD, slab[(t + 1) & 1], tid);
      stage64(VB + (size_t)(t + 1) * 64, SS, slab[2 + ((t + 1) & 1)], tid);
      SBAR();
    }
    const _Float16* kl = slab[t & 1];
    const _Float16* vl = slab[2 + (t & 1)];
#pragma unroll
    for (int kt = 0; kt < 4; ++kt) {
      const _Float16* kb = kl + (kt * 16 + c) * 64;
      half8 kf0 = *(const half8*)(kb + (((16 * g) ^ swz) >> 1));
      half8 kf1 = *(const half8*)(kb + (((64 + 16 * g) ^ swz) >> 1));
      f32x4 s = {0.f, 0.f, 0.f, 0.f};
      s = __builtin_amdgcn_mfma_f32_16x16x32_f16(kf0, qa0, s, 0, 0, 0);
      s = __builtin_amdgcn_mfma_f32_16x16x32_f16(kf1, qa1, s, 0, 0, 0);

      float p0 = exp2f(fmaf(s[0], L2E, ac));
      float p1 = exp2f(fmaf(s[1], L2E, ac));
      float p2 = exp2f(fmaf(s[2], L2E, ac));
      float p3 = exp2f(fmaf(s[3], L2E, ac));
      f32x4 st = {p0, p1, p2, p3};
      *(f32x4*)(attn_out + (qr + c) * SS + t * 64 + kt * 16 + 4 * g) = st;

      half4 pf;
      pf[0] = (_Float16)p0; pf[1] = (_Float16)p1;
      pf[2] = (_Float16)p2; pf[3] = (_Float16)p3;
#pragma unroll
      for (int dt = 0; dt < 4; ++dt) {
        const _Float16* vb = vl + (dt * 16 + c) * 64;
        half4 vf = *(const half4*)(vb + (((32 * kt + 8 * g) ^ swz) >> 1));
        cacc[dt] = __builtin_amdgcn_mfma_f32_16x16x16f16(pf, vf, cacc[dt], 0, 0, 0);
      }
    }
  }

  // ---- ctx store (wave-local, fully reduced) ----
#pragma unroll
  for (int dt = 0; dt < 4; ++dt)
#pragma unroll
    for (int j = 0; j < 4; ++j)
      ctx_out[(qr + 4 * g + j) * DD + dt * 16 + c] = cacc[dt][j];
}

extern "C" void kernel_launch(void* const* d_in, const int* in_sizes, int n_in,
                              void* d_out, int out_size, void* d_ws, size_t ws_size,
                              hipStream_t stream) {
  const float* q = (const float*)d_in[0];
  const float* k = (const float*)d_in[1];
  const float* v = (const float*)d_in[2];
  float* ctx = (float*)d_out;
  float* attn = ctx + (size_t)BB * SS * DD;
  _Float16* Kh = (_Float16*)d_ws;                 // [B][S][D] f16, 4 MB
  _Float16* VT = Kh + (size_t)BB * SS * DD;       // [B][D][S] f16, 4 MB
  setup_kernel<<<dim3(BB * 32), dim3(256), 0, stream>>>(k, v, Kh, VT);
  attn_kernel<<<dim3(BB * 64), dim3(128), 0, stream>>>(q, Kh, VT, ctx, attn);
}

// Round 19
// 94.370 us; speedup vs baseline: 1.2946x; 1.0383x over previous
//
#include <hip/hip_runtime.h>

#define BB 16
#define SS 2048
#define DD 64
#define L2E 1.44269504f
#define A3C 4.32808512f   // 3 * log2(e)

typedef _Float16 half8 __attribute__((ext_vector_type(8)));
typedef _Float16 half4 __attribute__((ext_vector_type(4)));
typedef float f32x4 __attribute__((ext_vector_type(4)));

typedef const __attribute__((address_space(1))) void* gas_ptr;
typedef __attribute__((address_space(3))) void* las_ptr;

#define SBAR() __builtin_amdgcn_sched_barrier(0)

// counted (non-draining) vmem wait + barrier; segment boundary for the ladders
#define TILE_SYNC(N)                                            \
  do {                                                          \
    asm volatile("s_waitcnt vmcnt(" #N ")" ::: "memory");       \
    __builtin_amdgcn_s_barrier();                               \
    __builtin_amdgcn_sched_barrier(0);                          \
  } while (0)

// ---------------- setup: K -> f16 copy, V -> f16 transposed [b][d][s] ----------------
__global__ __launch_bounds__(256) void setup_kernel(const float* __restrict__ K,
                                                    const float* __restrict__ V,
                                                    _Float16* __restrict__ Kh,
                                                    _Float16* __restrict__ VT) {
  __shared__ float tile[64][65];
  int b = blockIdx.x >> 5, kt = blockIdx.x & 31;  // 32 tiles of 64 rows
  int tid = threadIdx.x;
  size_t base = ((size_t)b * SS + (size_t)kt * 64) * DD;
  const float4* Kq = (const float4*)(K + base);
  const float4* Vq = (const float4*)(V + base);
  half4* Khq = (half4*)(Kh + base);
#pragma unroll
  for (int it = 0; it < 4; ++it) {
    int i = tid + it * 256;  // quad index 0..1023 over 64x64 tile
    float4 kv = Kq[i];
    half4 h;
    h[0] = (_Float16)kv.x; h[1] = (_Float16)kv.y;
    h[2] = (_Float16)kv.z; h[3] = (_Float16)kv.w;
    Khq[i] = h;
    float4 vv = Vq[i];
    int row = i >> 4, c4 = (i & 15) << 2;
    tile[row][c4 + 0] = vv.x; tile[row][c4 + 1] = vv.y;
    tile[row][c4 + 2] = vv.z; tile[row][c4 + 3] = vv.w;
  }
  __syncthreads();
  int d = tid >> 2, seg = tid & 3;  // 64 d-rows x 4 segments of 16 k
  half8 o0, o1;
#pragma unroll
  for (int j = 0; j < 8; ++j) o0[j] = (_Float16)tile[seg * 16 + j][d];
#pragma unroll
  for (int j = 0; j < 8; ++j) o1[j] = (_Float16)tile[seg * 16 + 8 + j][d];
  _Float16* dst = VT + ((size_t)b * DD + d) * SS + (size_t)kt * 64 + seg * 16;
  *(half8*)dst = o0;
  *(half8*)(dst + 8) = o1;
}

// Stage one 64x64 f16 tile into an 8KB LDS slab with a 2-wave (128-thread) block.
// XOR-swizzle applied on the GLOBAL source (global_load_lds writes lane-linear).
// 4 x 16B loads per thread; wave w covers rows w*32 .. w*32+31.
__device__ __forceinline__ void stage64(const _Float16* __restrict__ gbase, size_t rstride,
                                        _Float16* lds, int tid) {
  int w = tid >> 6, lam = tid & 63;
#pragma unroll
  for (int a = 0; a < 4; ++a) {
    int rloc = lam >> 3;                              // 0..7 (== r & 7)
    int r = w * 32 + a * 8 + rloc;
    int byt = ((lam & 7) * 16) ^ (rloc << 4);         // swizzled byte-in-row
    const _Float16* g = gbase + (size_t)r * rstride + (byt >> 1);
    _Float16* lp = lds + (w * 32 + a * 8) * 64;       // wave-uniform base
    __builtin_amdgcn_global_load_lds((gas_ptr)g, (las_ptr)lp, 16, 0, 0);
  }
}

__device__ __forceinline__ void load_qfrag(const float* __restrict__ Qp,
                                           half8& qa0, half8& qa1) {
  float4 v0 = *(const float4*)(Qp);
  float4 v1 = *(const float4*)(Qp + 4);
  float4 v2 = *(const float4*)(Qp + 32);
  float4 v3 = *(const float4*)(Qp + 36);
  qa0[0] = (_Float16)(v0.x * 0.125f); qa0[1] = (_Float16)(v0.y * 0.125f);
  qa0[2] = (_Float16)(v0.z * 0.125f); qa0[3] = (_Float16)(v0.w * 0.125f);
  qa0[4] = (_Float16)(v1.x * 0.125f); qa0[5] = (_Float16)(v1.y * 0.125f);
  qa0[6] = (_Float16)(v1.z * 0.125f); qa0[7] = (_Float16)(v1.w * 0.125f);
  qa1[0] = (_Float16)(v2.x * 0.125f); qa1[1] = (_Float16)(v2.y * 0.125f);
  qa1[2] = (_Float16)(v2.z * 0.125f); qa1[3] = (_Float16)(v2.w * 0.125f);
  qa1[4] = (_Float16)(v3.x * 0.125f); qa1[5] = (_Float16)(v3.y * 0.125f);
  qa1[6] = (_Float16)(v3.z * 0.125f); qa1[7] = (_Float16)(v3.w * 0.125f);
}

// ---------------- fused attention: 2-wave blocks, two sweeps, exact counted vmcnt ------
// wg = 2 waves x 16 q-rows = 32 rows; waves share 4 x 8KB staged slabs, sweep all k.
__global__ __launch_bounds__(128, 2) void attn_kernel(const float* __restrict__ Q,
                                                      const _Float16* __restrict__ Kh,
                                                      const _Float16* __restrict__ VT,
                                                      float* __restrict__ ctx_out,
                                                      float* __restrict__ attn_out) {
  __shared__ __attribute__((aligned(16))) _Float16 slab[4][64 * 64];  // 32KB total

  int tid = threadIdx.x;
  int w = tid >> 6, l = tid & 63, g = l >> 4, c = l & 15;
  int bid = (int)blockIdx.x;
  int remap = (bid & 7) * 128 + (bid >> 3);   // XCD-contiguous (1024 grid, 2 batches/XCD)
  int b = remap >> 6, qb = remap & 63;
  size_t qr = (size_t)b * SS + (size_t)qb * 32 + (size_t)w * 16;
  const _Float16* KB = Kh + (size_t)b * SS * DD;
  const _Float16* VB = VT + (size_t)b * DD * SS;
  int swz = (c & 7) << 4;

  // ---- sweep 1 prologue (pinned order: Q | s0 | s1) ----
  half8 qa0, qa1;
  load_qfrag(Q + (qr + c) * DD + 8 * g, qa0, qa1);
  SBAR();
  stage64(KB, DD, slab[0], tid);
  SBAR();
  stage64(KB + (size_t)64 * DD, DD, slab[1], tid);
  SBAR();

  // ---- sweep 1: row sums of exp(s - 3); depth-2, 4 slabs ----
  // Ladder (issue-order pinned): t=0: [Q4,s0,s1] -> vmcnt(4) retires Q+s0;
  // steady: [s(t),s(t+1)] -> vmcnt(4); t=31: [s31] -> vmcnt(0).
  float lsum = 0.f;
  for (int t = 0; t < 32; ++t) {
    if (t < 31) TILE_SYNC(4); else TILE_SYNC(0);
    if (t + 2 < 32) {
      stage64(KB + (size_t)(t + 2) * 64 * DD, DD, slab[(t + 2) & 3], tid);
      SBAR();
    }
    const _Float16* kl = slab[t & 3];
#pragma unroll
    for (int kt = 0; kt < 4; ++kt) {
      const _Float16* kb = kl + (kt * 16 + c) * 64;
      half8 kf0 = *(const half8*)(kb + (((16 * g) ^ swz) >> 1));
      half8 kf1 = *(const half8*)(kb + (((64 + 16 * g) ^ swz) >> 1));
      f32x4 s = {0.f, 0.f, 0.f, 0.f};
      s = __builtin_amdgcn_mfma_f32_16x16x32_f16(kf0, qa0, s, 0, 0, 0);
      s = __builtin_amdgcn_mfma_f32_16x16x32_f16(kf1, qa1, s, 0, 0, 0);
      lsum += exp2f(fmaf(s[0], L2E, -A3C)) + exp2f(fmaf(s[1], L2E, -A3C)) +
              exp2f(fmaf(s[2], L2E, -A3C)) + exp2f(fmaf(s[3], L2E, -A3C));
    }
  }
  lsum += __shfl_xor(lsum, 16);
  lsum += __shfl_xor(lsum, 32);
  float ac = -__log2f(lsum) - A3C;  // p/l = exp2(s*L2E + ac)

  __syncthreads();  // all waves done reading slabs before restage

  // ---- sweep 2 prologue (pinned: KV0 | KV1); K slabs {0,1}, V slabs {2,3} ----
  stage64(KB, DD, slab[0], tid);
  stage64(VB, SS, slab[2], tid);
  SBAR();
  stage64(KB + (size_t)64 * DD, DD, slab[1], tid);
  stage64(VB + 64, SS, slab[3], tid);
  SBAR();

  // ---- sweep 2: recompute S, write normalized attn, PV; 2+2 slabs, depth-1 ----
  // Ladder: t=0: [KV0 8, KV1 8] -> vmcnt(8) retires KV0;
  // t>=1: [st(t-2)?, KV(t), st(t-1)] -> vmcnt(4) retires KV(t) (+old store acks).
  // Seg(t), 1<=t<=30, pinned: stage KV(t+1) first (slab parity (t+1)&1; safe: all
  // waves passed sync(t) so compute(t-1) reads of that slab are done), then compute.
  f32x4 cacc[4] = {{0.f, 0.f, 0.f, 0.f}, {0.f, 0.f, 0.f, 0.f},
                   {0.f, 0.f, 0.f, 0.f}, {0.f, 0.f, 0.f, 0.f}};
  for (int t = 0; t < 32; ++t) {
    if (t == 0) TILE_SYNC(8); else TILE_SYNC(4);
    if (t >= 1 && t <= 30) {
      stage64(KB + (size_t)(t + 1) * 64 * DD, DD, slab[(t + 1) & 1], tid);
      stage64(VB + (size_t)(t + 1) * 64, SS, slab[2 + ((t + 1) & 1)], tid);
      SBAR();
    }
    const _Float16* kl = slab[t & 1];
    const _Float16* vl = slab[2 + (t & 1)];
#pragma unroll
    for (int kt = 0; kt < 4; ++kt) {
      const _Float16* kb = kl + (kt * 16 + c) * 64;
      half8 kf0 = *(const half8*)(kb + (((16 * g) ^ swz) >> 1));
      half8 kf1 = *(const half8*)(kb + (((64 + 16 * g) ^ swz) >> 1));
      f32x4 s = {0.f, 0.f, 0.f, 0.f};
      s = __builtin_amdgcn_mfma_f32_16x16x32_f16(kf0, qa0, s, 0, 0, 0);
      s = __builtin_amdgcn_mfma_f32_16x16x32_f16(kf1, qa1, s, 0, 0, 0);

      float p0 = exp2f(fmaf(s[0], L2E, ac));
      float p1 = exp2f(fmaf(s[1], L2E, ac));
      float p2 = exp2f(fmaf(s[2], L2E, ac));
      float p3 = exp2f(fmaf(s[3], L2E, ac));
      f32x4 st = {p0, p1, p2, p3};
      *(f32x4*)(attn_out + (qr + c) * SS + t * 64 + kt * 16 + 4 * g) = st;

      half4 pf;
      pf[0] = (_Float16)p0; pf[1] = (_Float16)p1;
      pf[2] = (_Float16)p2; pf[3] = (_Float16)p3;
#pragma unroll
      for (int dt = 0; dt < 4; ++dt) {
        const _Float16* vb = vl + (dt * 16 + c) * 64;
        half4 vf = *(const half4*)(vb + (((32 * kt + 8 * g) ^ swz) >> 1));
        cacc[dt] = __builtin_amdgcn_mfma_f32_16x16x16f16(pf, vf, cacc[dt], 0, 0, 0);
      }
    }
  }

  // ---- ctx store (wave-local, fully reduced) ----
#pragma unroll
  for (int dt = 0; dt < 4; ++dt)
#pragma unroll
    for (int j = 0; j < 4; ++j)
      ctx_out[(qr + 4 * g + j) * DD + dt * 16 + c] = cacc[dt][j];
}

extern "C" void kernel_launch(void* const* d_in, const int* in_sizes, int n_in,
                              void* d_out, int out_size, void* d_ws, size_t ws_size,
                              hipStream_t stream) {
  const float* q = (const float*)d_in[0];
  const float* k = (const float*)d_in[1];
  const float* v = (const float*)d_in[2];
  float* ctx = (float*)d_out;
  float* attn = ctx + (size_t)BB * SS * DD;
  _Float16* Kh = (_Float16*)d_ws;                 // [B][S][D] f16, 4 MB
  _Float16* VT = Kh + (size_t)BB * SS * DD;       // [B][D][S] f16, 4 MB
  setup_kernel<<<dim3(BB * 32), dim3(256), 0, stream>>>(k, v, Kh, VT);
  attn_kernel<<<dim3(BB * 64), dim3(128), 0, stream>>>(q, Kh, VT, ctx, attn);
}